// Round 2
// baseline (2744.688 us; speedup 1.0000x reference)
//
#include <hip/hip_runtime.h>

#define N_NODES 100096
#define N_EDGES 1601536
#define NGRAPH  128
#define NPG     782
#define HDIM    128
#define CDIM    10

// ---------------------------------------------------------------- degree / CSR
__global__ __launch_bounds__(256) void deg_kernel(const int* __restrict__ src,
                                                  const int* __restrict__ dst,
                                                  int* __restrict__ cnt_src,
                                                  int* __restrict__ cnt_dst) {
  int i = blockIdx.x * 256 + threadIdx.x;
  int stride = gridDim.x * 256;
  for (; i < N_EDGES; i += stride) {
    atomicAdd(&cnt_src[src[i]], 1);
    atomicAdd(&cnt_dst[dst[i]], 1);
  }
}

__global__ __launch_bounds__(256) void inv_kernel(const int* __restrict__ cs,
                                                  const int* __restrict__ cd,
                                                  float* __restrict__ iso,
                                                  float* __restrict__ isi) {
  int i = blockIdx.x * 256 + threadIdx.x;
  if (i < N_NODES) {
    int a = cs[i] > 1 ? cs[i] : 1;
    int b = cd[i] > 1 ? cd[i] : 1;
    iso[i] = 1.0f / sqrtf((float)a);
    isi[i] = 1.0f / sqrtf((float)b);
  }
}

__global__ __launch_bounds__(256) void scan1_kernel(const int* __restrict__ cnt,
                                                    int* __restrict__ out,
                                                    int* __restrict__ bsum) {
  __shared__ int sh[256];
  int tid = threadIdx.x;
  int base = blockIdx.x * 1024 + tid * 4;
  int v[4]; int tsum = 0;
  #pragma unroll
  for (int t = 0; t < 4; t++) { int idx = base + t; v[t] = (idx < N_NODES) ? cnt[idx] : 0; tsum += v[t]; }
  sh[tid] = tsum;
  for (int off = 1; off < 256; off <<= 1) {
    __syncthreads();
    int add = (tid >= off) ? sh[tid - off] : 0;
    __syncthreads();
    sh[tid] += add;
  }
  __syncthreads();
  int excl = sh[tid] - tsum;
  #pragma unroll
  for (int t = 0; t < 4; t++) { int idx = base + t; if (idx < N_NODES) out[idx] = excl; excl += v[t]; }
  if (tid == 255) bsum[blockIdx.x] = sh[255];
}

__global__ void scan2_kernel(int* __restrict__ bsum, int nb) {
  if (blockIdx.x == 0 && threadIdx.x == 0) {
    int run = 0;
    for (int i = 0; i < nb; i++) { int t = bsum[i]; bsum[i] = run; run += t; }
  }
}

__global__ __launch_bounds__(256) void scan3_kernel(int* __restrict__ out,
                                                    const int* __restrict__ bsum) {
  int add = bsum[blockIdx.x];
  int base = blockIdx.x * 1024 + threadIdx.x * 4;
  #pragma unroll
  for (int t = 0; t < 4; t++) { int idx = base + t; if (idx < N_NODES) out[idx] += add; }
  if (blockIdx.x == 0 && threadIdx.x == 0) out[N_NODES] = N_EDGES;
}

__global__ __launch_bounds__(256) void scatter_kernel(const int* __restrict__ src,
                                                      const int* __restrict__ dst,
                                                      const int* __restrict__ off,
                                                      int* __restrict__ pos,
                                                      int* __restrict__ csr_src) {
  int i = blockIdx.x * 256 + threadIdx.x;
  for (; i < N_EDGES; i += gridDim.x * 256) {
    int d = dst[i];
    int p = off[d] + atomicAdd(&pos[d], 1);
    csr_src[p] = src[i];
  }
}

// ---------------------------------------------------------------- aggregation
// one wave per dst node; lane holds channels [2*lane, 2*lane+1]
__global__ __launch_bounds__(256) void agg_kernel(const float* __restrict__ x,
                                                  const int* __restrict__ off,
                                                  const int* __restrict__ csr_src,
                                                  const float* __restrict__ iso,
                                                  const float* __restrict__ isi,
                                                  float* __restrict__ agg) {
  int wave = (blockIdx.x * 256 + threadIdx.x) >> 6;
  int lane = threadIdx.x & 63;
  if (wave >= N_NODES) return;
  const float2* x2 = (const float2*)x;
  int beg = off[wave], end = off[wave + 1];
  float ax = 0.f, ay = 0.f;
  int j = beg;
  for (; j + 1 < end; j += 2) {
    int s0 = csr_src[j], s1 = csr_src[j + 1];
    float w0 = iso[s0], w1 = iso[s1];
    float2 v0 = x2[s0 * 64 + lane];
    float2 v1 = x2[s1 * 64 + lane];
    ax += w0 * v0.x + w1 * v1.x;
    ay += w0 * v0.y + w1 * v1.y;
  }
  if (j < end) {
    int s0 = csr_src[j];
    float w0 = iso[s0];
    float2 v0 = x2[s0 * 64 + lane];
    ax += w0 * v0.x;
    ay += w0 * v0.y;
  }
  float si = isi[wave];
  ((float2*)agg)[wave * 64 + lane] = make_float2(ax * si, ay * si);
}

// ---------------------------------------------------------------- generic f32 GEMM
// C[M,Nc] = A[M,K] @ W[K,Nc] + bias, optional relu.
// AMODE 0: plain A (row stride K). AMODE 1: A = concat(hg[row/NPG] (256), x[row] (128)), K=384.
// Block 256 threads, 64x64 output tile, 4x4 per thread.
template <int AMODE>
__global__ __launch_bounds__(256) void gemm_f32(const float* __restrict__ A,
                                                const float* __restrict__ A2,
                                                const float* __restrict__ W,
                                                const float* __restrict__ bias,
                                                float* __restrict__ C,
                                                int M, int K, int Nc, int relu) {
  __shared__ float As[64 * 68];
  __shared__ float Ws[64 * 68];
  int tid = threadIdx.x;
  int tx = tid & 15, ty = tid >> 4;
  int m0 = blockIdx.x * 64, c0 = blockIdx.y * 64;
  float4 acc[4];
  #pragma unroll
  for (int i = 0; i < 4; i++) acc[i] = make_float4(0.f, 0.f, 0.f, 0.f);

  int nChunks = (K + 63) >> 6;
  for (int kc = 0; kc < nChunks; ++kc) {
    int kbase = kc * 64;
    // stage A tile [64][64]
    #pragma unroll
    for (int it = 0; it < 4; ++it) {
      int row = it * 16 + ty;
      int kl = tx * 4;
      int kg = kbase + kl;
      int gr = m0 + row;
      float4 v = make_float4(0.f, 0.f, 0.f, 0.f);
      if (AMODE == 0) {
        if (kg + 3 < K) {
          v = *(const float4*)&A[(size_t)gr * K + kg];
        } else {
          float tmp[4] = {0.f, 0.f, 0.f, 0.f};
          #pragma unroll
          for (int j = 0; j < 4; j++) if (kg + j < K) tmp[j] = A[(size_t)gr * K + kg + j];
          v = make_float4(tmp[0], tmp[1], tmp[2], tmp[3]);
        }
      } else {
        if (kg < 256) v = *(const float4*)&A[(size_t)(gr / NPG) * 256 + kg];
        else          v = *(const float4*)&A2[(size_t)gr * HDIM + (kg - 256)];
      }
      *(float4*)&As[row * 68 + kl] = v;
    }
    // stage W tile [64][64] (guarded scalar loads; W is small & L2-hot)
    #pragma unroll
    for (int it = 0; it < 4; ++it) {
      int kk = it * 16 + ty;
      int col = tx * 4;
      int kg = kbase + kk;
      float tmp[4];
      #pragma unroll
      for (int j = 0; j < 4; j++) {
        int c = c0 + col + j;
        tmp[j] = (kg < K && c < Nc) ? W[(size_t)kg * Nc + c] : 0.f;
      }
      *(float4*)&Ws[kk * 68 + col] = make_float4(tmp[0], tmp[1], tmp[2], tmp[3]);
    }
    __syncthreads();
    #pragma unroll
    for (int kk = 0; kk < 64; kk += 4) {
      float4 w0 = *(const float4*)&Ws[(kk + 0) * 68 + tx * 4];
      float4 w1 = *(const float4*)&Ws[(kk + 1) * 68 + tx * 4];
      float4 w2 = *(const float4*)&Ws[(kk + 2) * 68 + tx * 4];
      float4 w3 = *(const float4*)&Ws[(kk + 3) * 68 + tx * 4];
      #pragma unroll
      for (int i = 0; i < 4; i++) {
        float4 a = *(const float4*)&As[(ty * 4 + i) * 68 + kk];
        acc[i].x += a.x * w0.x + a.y * w1.x + a.z * w2.x + a.w * w3.x;
        acc[i].y += a.x * w0.y + a.y * w1.y + a.z * w2.y + a.w * w3.y;
        acc[i].z += a.x * w0.z + a.y * w1.z + a.z * w2.z + a.w * w3.z;
        acc[i].w += a.x * w0.w + a.y * w1.w + a.z * w2.w + a.w * w3.w;
      }
    }
    __syncthreads();
  }
  // epilogue
  #pragma unroll
  for (int i = 0; i < 4; i++) {
    int row = m0 + ty * 4 + i;
    float vals[4] = {acc[i].x, acc[i].y, acc[i].z, acc[i].w};
    #pragma unroll
    for (int j = 0; j < 4; j++) {
      int c = c0 + tx * 4 + j;
      if (c < Nc) {
        float v = vals[j] + bias[c];
        if (relu) v = fmaxf(v, 0.f);
        C[(size_t)row * Nc + c] = v;
      }
    }
  }
}

// ---------------------------------------------------------------- BN pieces
__global__ __launch_bounds__(256) void col_stats(const float* __restrict__ h,
                                                 float* __restrict__ sums) {
  __shared__ float sh[256];
  int c = threadIdx.x & 127, half = threadIdx.x >> 7;
  float s = 0.f, q = 0.f;
  for (int r = blockIdx.x * 2 + half; r < N_NODES; r += gridDim.x * 2) {
    float v = h[(size_t)r * HDIM + c];
    s += v; q += v * v;
  }
  sh[threadIdx.x] = s;
  __syncthreads();
  if (threadIdx.x < 128) atomicAdd(&sums[c], sh[threadIdx.x] + sh[threadIdx.x + 128]);
  __syncthreads();
  sh[threadIdx.x] = q;
  __syncthreads();
  if (threadIdx.x < 128) atomicAdd(&sums[128 + c], sh[threadIdx.x] + sh[threadIdx.x + 128]);
}

__global__ void bn_finalize(const float* __restrict__ sums,
                            const float* __restrict__ gamma,
                            const float* __restrict__ beta,
                            float* __restrict__ sc) {
  int c = threadIdx.x;  // 128
  float mu = sums[c] / (float)N_NODES;
  float var = sums[128 + c] / (float)N_NODES - mu * mu;
  float s = gamma[c] / sqrtf(var + 1e-5f);
  sc[c] = s;
  sc[128 + c] = beta[c] - mu * s;
}

// x += relu(h*scale + shift)   (float4 over N*128)
__global__ __launch_bounds__(256) void bn_apply(const float* __restrict__ h,
                                                const float* __restrict__ sc,
                                                float* __restrict__ x) {
  const float4* h4 = (const float4*)h;
  const float4* s4 = (const float4*)sc;
  float4* x4 = (float4*)x;
  int i = blockIdx.x * 256 + threadIdx.x;
  int stride = gridDim.x * 256;
  for (; i < N_NODES * 32; i += stride) {
    int c4 = i & 31;
    float4 hv = h4[i];
    float4 sv = s4[c4];
    float4 bv = s4[32 + c4];
    float4 xv = x4[i];
    xv.x += fmaxf(hv.x * sv.x + bv.x, 0.f);
    xv.y += fmaxf(hv.y * sv.y + bv.y, 0.f);
    xv.z += fmaxf(hv.z * sv.z + bv.z, 0.f);
    xv.w += fmaxf(hv.w * sv.w + bv.w, 0.f);
    x4[i] = xv;
  }
}

// ---------------------------------------------------------------- pooling / labels
__global__ __launch_bounds__(256) void pool_kernel(const float* __restrict__ x,
                                                   float* __restrict__ hg) {
  __shared__ float sh[512];
  int b = blockIdx.x;
  int c = threadIdx.x & 127, half = threadIdx.x >> 7;
  const float* xb = x + (size_t)b * NPG * HDIM;
  float s = 0.f, m = -3.4e38f;
  for (int r = half; r < NPG; r += 2) {
    float v = xb[(size_t)r * HDIM + c];
    s += v;
    m = fmaxf(m, v);
  }
  sh[threadIdx.x] = s;
  sh[256 + threadIdx.x] = m;
  __syncthreads();
  if (threadIdx.x < 128) {
    hg[b * 256 + c] = (sh[threadIdx.x] + sh[128 + threadIdx.x]) / (float)NPG;
    hg[b * 256 + 128 + c] = fmaxf(sh[256 + threadIdx.x], sh[384 + threadIdx.x]);
  }
}

__global__ __launch_bounds__(256) void label_kernel(const int* __restrict__ labels,
                                                    float* __restrict__ out) {
  int i = blockIdx.x * 256 + threadIdx.x;
  if (i < N_NODES) out[i] = (float)labels[i / NPG];
}

// ---------------------------------------------------------------- launch
extern "C" void kernel_launch(void* const* d_in, const int* in_sizes, int n_in,
                              void* d_out, int out_size, void* d_ws, size_t ws_size,
                              hipStream_t stream) {
  const float* feature  = (const float*)d_in[0];
  const int*   esrc     = (const int*)d_in[1];
  const int*   edst     = (const int*)d_in[2];
  const int*   labels   = (const int*)d_in[3];
  const float* W_emb    = (const float*)d_in[4];
  const float* b_emb    = (const float*)d_in[5];
  const float* gcn_W    = (const float*)d_in[6];
  const float* gcn_b    = (const float*)d_in[7];
  const float* gcn_g    = (const float*)d_in[8];
  const float* gcn_be   = (const float*)d_in[9];
  const float* gW1 = (const float*)d_in[10];
  const float* gb1 = (const float*)d_in[11];
  const float* gW2 = (const float*)d_in[12];
  const float* gb2 = (const float*)d_in[13];
  const float* gW3 = (const float*)d_in[14];
  const float* gb3 = (const float*)d_in[15];
  const float* nW1 = (const float*)d_in[16];
  const float* nb1 = (const float*)d_in[17];
  const float* nW2 = (const float*)d_in[18];
  const float* nb2 = (const float*)d_in[19];
  const float* nW3 = (const float*)d_in[20];
  const float* nb3 = (const float*)d_in[21];

  // output layout: x [N,128] | x_g [N,10] | g [128,10] | node_label [N]
  float* x     = (float*)d_out;
  float* outXG = x + (size_t)N_NODES * HDIM;
  float* outG  = outXG + (size_t)N_NODES * CDIM;
  float* outLb = outG + NGRAPH * CDIM;

  // workspace layout (bytes)
  char* ws = (char*)d_ws;
  float* iso     = (float*)(ws + 0);               // N f32
  float* isi     = (float*)(ws + 400384);          // N f32
  int*   cnt_src = (int*)  (ws + 800768);          // N int
  int*   cnt_dst = (int*)  (ws + 1201152);         // N int
  int*   pos     = (int*)  (ws + 1601536);         // N int
  int*   csr_off = (int*)  (ws + 2001920);         // N+1 int
  int*   bsum    = (int*)  (ws + 2402560);         // 128 int
  float* bnsum   = (float*)(ws + 2403072);         // 256 f32
  float* bnsc    = (float*)(ws + 2404096);         // 256 f32
  float* hg      = (float*)(ws + 2405120);         // 128*256 f32
  float* g1      = (float*)(ws + 2536192);         // 128*128
  float* g2      = (float*)(ws + 2601728);         // 128*64
  int*   csr_src = (int*)  (ws + 2634496);         // E int
  float* bigA    = (float*)(ws + 9040640);         // N*192 f32 (agg / t1)
  float* bigB    = (float*)(ws + 85914368);        // N*128 f32 (h / t2)

  float* agg = bigA;
  float* h   = bigB;
  float* t1  = bigA;
  float* t2  = bigB;

  // ---- degrees + CSR build
  hipMemsetAsync(cnt_src, 0, (size_t)N_NODES * 4, stream);
  hipMemsetAsync(cnt_dst, 0, (size_t)N_NODES * 4, stream);
  hipMemsetAsync(pos,     0, (size_t)N_NODES * 4, stream);
  deg_kernel<<<2048, 256, 0, stream>>>(esrc, edst, cnt_src, cnt_dst);
  inv_kernel<<<(N_NODES + 255) / 256, 256, 0, stream>>>(cnt_src, cnt_dst, iso, isi);
  scan1_kernel<<<98, 256, 0, stream>>>(cnt_dst, csr_off, bsum);
  scan2_kernel<<<1, 1, 0, stream>>>(bsum, 98);
  scan3_kernel<<<98, 256, 0, stream>>>(csr_off, bsum);
  scatter_kernel<<<2048, 256, 0, stream>>>(esrc, edst, csr_off, pos, csr_src);

  // ---- embedding: x = feature @ W_emb + b_emb
  gemm_f32<0><<<dim3(N_NODES / 64, 2), 256, 0, stream>>>(feature, nullptr, W_emb, b_emb, x,
                                                         N_NODES, 128, 128, 0);

  // ---- GCN layers
  for (int l = 0; l < 3; ++l) {
    hipMemsetAsync(bnsum, 0, 1024, stream);
    agg_kernel<<<N_NODES / 4, 256, 0, stream>>>(x, csr_off, csr_src, iso, isi, agg);
    gemm_f32<0><<<dim3(N_NODES / 64, 2), 256, 0, stream>>>(agg, nullptr,
                                                           gcn_W + (size_t)l * 128 * 128,
                                                           gcn_b + l * 128, h,
                                                           N_NODES, 128, 128, 0);
    col_stats<<<512, 256, 0, stream>>>(h, bnsum);
    bn_finalize<<<1, 128, 0, stream>>>(bnsum, gcn_g + l * 128, gcn_be + l * 128, bnsc);
    bn_apply<<<2048, 256, 0, stream>>>(h, bnsc, x);
  }

  // ---- pooling
  pool_kernel<<<NGRAPH, 256, 0, stream>>>(x, hg);

  // ---- graph head: 256 -> 128 -> 64 -> 10
  gemm_f32<0><<<dim3(2, 2), 256, 0, stream>>>(hg, nullptr, gW1, gb1, g1, NGRAPH, 256, 128, 1);
  gemm_f32<0><<<dim3(2, 1), 256, 0, stream>>>(g1, nullptr, gW2, gb2, g2, NGRAPH, 128, 64, 1);
  gemm_f32<0><<<dim3(2, 1), 256, 0, stream>>>(g2, nullptr, gW3, gb3, outG, NGRAPH, 64, 10, 0);

  // ---- node head: concat(hg[seg], x) [N,384] -> 192 -> 96 -> 10
  gemm_f32<1><<<dim3(N_NODES / 64, 3), 256, 0, stream>>>(hg, x, nW1, nb1, t1, N_NODES, 384, 192, 1);
  gemm_f32<0><<<dim3(N_NODES / 64, 2), 256, 0, stream>>>(t1, nullptr, nW2, nb2, t2, N_NODES, 192, 96, 1);
  gemm_f32<0><<<dim3(N_NODES / 64, 1), 256, 0, stream>>>(t2, nullptr, nW3, nb3, outXG, N_NODES, 96, 10, 0);

  // ---- node labels
  label_kernel<<<(N_NODES + 255) / 256, 256, 0, stream>>>(labels, outLb);
}

// Round 6
// 1362.568 us; speedup vs baseline: 2.0143x; 2.0143x over previous
//
#include <hip/hip_runtime.h>

#define N_NODES 100096
#define N_EDGES 1601536
#define NGRAPH  128
#define NPG     782
#define HDIM    128
#define CDIM    10

typedef unsigned short u16;
typedef short short8 __attribute__((ext_vector_type(8)));
typedef float floatx4 __attribute__((ext_vector_type(4)));

// ---- bf16 split helpers (RNE) : f ~= hi + lo, |err| ~ 2^-16 |f|
__device__ __forceinline__ u16 bfh(float f) {
  unsigned u = __float_as_uint(f);
  u += 0x7FFFu + ((u >> 16) & 1u);
  return (u16)(u >> 16);
}
__device__ __forceinline__ float bff(u16 h) {
  return __uint_as_float(((unsigned)h) << 16);
}
__device__ __forceinline__ void split2(float f, u16& hi, u16& lo) {
  hi = bfh(f);
  lo = bfh(f - bff(hi));
}

// ---------------------------------------------------------------- degree / CSR
__global__ __launch_bounds__(256) void deg_kernel(const int* __restrict__ src,
                                                  const int* __restrict__ dst,
                                                  int* __restrict__ cnt_src,
                                                  int* __restrict__ cnt_dst) {
  int i = blockIdx.x * 256 + threadIdx.x;
  int stride = gridDim.x * 256;
  for (; i < N_EDGES; i += stride) {
    atomicAdd(&cnt_src[src[i]], 1);
    atomicAdd(&cnt_dst[dst[i]], 1);
  }
}

__global__ __launch_bounds__(256) void inv_kernel(const int* __restrict__ cs,
                                                  const int* __restrict__ cd,
                                                  float* __restrict__ iso,
                                                  float* __restrict__ isi) {
  int i = blockIdx.x * 256 + threadIdx.x;
  if (i < N_NODES) {
    int a = cs[i] > 1 ? cs[i] : 1;
    int b = cd[i] > 1 ? cd[i] : 1;
    iso[i] = 1.0f / sqrtf((float)a);
    isi[i] = 1.0f / sqrtf((float)b);
  }
}

__global__ __launch_bounds__(256) void scan1_kernel(const int* __restrict__ cnt,
                                                    int* __restrict__ out,
                                                    int* __restrict__ bsum) {
  __shared__ int sh[256];
  int tid = threadIdx.x;
  int base = blockIdx.x * 1024 + tid * 4;
  int v[4]; int tsum = 0;
  #pragma unroll
  for (int t = 0; t < 4; t++) { int idx = base + t; v[t] = (idx < N_NODES) ? cnt[idx] : 0; tsum += v[t]; }
  sh[tid] = tsum;
  for (int off = 1; off < 256; off <<= 1) {
    __syncthreads();
    int add = (tid >= off) ? sh[tid - off] : 0;
    __syncthreads();
    sh[tid] += add;
  }
  __syncthreads();
  int excl = sh[tid] - tsum;
  #pragma unroll
  for (int t = 0; t < 4; t++) { int idx = base + t; if (idx < N_NODES) out[idx] = excl; excl += v[t]; }
  if (tid == 255) bsum[blockIdx.x] = sh[255];
}

__global__ void scan2_kernel(int* __restrict__ bsum, int nb) {
  if (blockIdx.x == 0 && threadIdx.x == 0) {
    int run = 0;
    for (int i = 0; i < nb; i++) { int t = bsum[i]; bsum[i] = run; run += t; }
  }
}

__global__ __launch_bounds__(256) void scan3_kernel(int* __restrict__ out,
                                                    const int* __restrict__ bsum) {
  int add = bsum[blockIdx.x];
  int base = blockIdx.x * 1024 + threadIdx.x * 4;
  #pragma unroll
  for (int t = 0; t < 4; t++) { int idx = base + t; if (idx < N_NODES) out[idx] += add; }
  if (blockIdx.x == 0 && threadIdx.x == 0) out[N_NODES] = N_EDGES;
}

__global__ __launch_bounds__(256) void scatter_kernel(const int* __restrict__ src,
                                                      const int* __restrict__ dst,
                                                      const int* __restrict__ off,
                                                      int* __restrict__ pos,
                                                      int* __restrict__ csr_src) {
  int i = blockIdx.x * 256 + threadIdx.x;
  for (; i < N_EDGES; i += gridDim.x * 256) {
    int d = dst[i];
    int p = off[d] + atomicAdd(&pos[d], 1);
    csr_src[p] = src[i];
  }
}

// ---------------------------------------------------------------- splits
// f32 -> (hi,lo) bf16 pair, vectorized by 4
__global__ __launch_bounds__(256) void split_pair(const float* __restrict__ in,
                                                  u16* __restrict__ hi,
                                                  u16* __restrict__ lo, int n4) {
  int i = blockIdx.x * 256 + threadIdx.x;
  if (i >= n4) return;
  float4 v = ((const float4*)in)[i];
  u16 h0,l0,h1,l1,h2,l2,h3,l3;
  split2(v.x,h0,l0); split2(v.y,h1,l1); split2(v.z,h2,l2); split2(v.w,h3,l3);
  int2 ph = make_int2((int)h0 | ((int)h1<<16), (int)h2 | ((int)h3<<16));
  int2 pl = make_int2((int)l0 | ((int)l1<<16), (int)l2 | ((int)l3<<16));
  ((int2*)hi)[i] = ph;
  ((int2*)lo)[i] = pl;
}

// W [K][Nc] f32 -> Wt_hi/Wt_lo [Nc][K] bf16 (transposed for MFMA B staging)
__global__ __launch_bounds__(256) void wsplit(const float* __restrict__ W,
                                              u16* __restrict__ Thi,
                                              u16* __restrict__ Tlo, int K, int Nc) {
  int i = blockIdx.x * 256 + threadIdx.x;
  if (i >= K * Nc) return;
  int k = i / Nc, n = i - k * Nc;
  u16 h, l;
  split2(W[i], h, l);
  Thi[n * K + k] = h;
  Tlo[n * K + k] = l;
}

// ---------------------------------------------------------------- aggregation
// one wave per dst node; lane holds channels [2*lane, 2*lane+1]; unroll-4 for latency.
// Writes bf16 hi/lo pair (feeds MFMA GEMM directly; same bytes as f32).
__global__ __launch_bounds__(256) void agg_kernel(const float* __restrict__ x,
                                                  const int* __restrict__ off,
                                                  const int* __restrict__ csr_src,
                                                  const float* __restrict__ iso,
                                                  const float* __restrict__ isi,
                                                  u16* __restrict__ aggh,
                                                  u16* __restrict__ aggl) {
  int wave = (blockIdx.x * 256 + threadIdx.x) >> 6;
  int lane = threadIdx.x & 63;
  if (wave >= N_NODES) return;
  const float2* x2 = (const float2*)x;
  int beg = off[wave], end = off[wave + 1];
  float ax = 0.f, ay = 0.f;
  int j = beg;
  for (; j + 3 < end; j += 4) {
    int s0 = csr_src[j], s1 = csr_src[j+1], s2 = csr_src[j+2], s3 = csr_src[j+3];
    float w0 = iso[s0], w1 = iso[s1], w2 = iso[s2], w3 = iso[s3];
    float2 v0 = x2[s0*64+lane], v1 = x2[s1*64+lane], v2 = x2[s2*64+lane], v3 = x2[s3*64+lane];
    ax += w0*v0.x + w1*v1.x + w2*v2.x + w3*v3.x;
    ay += w0*v0.y + w1*v1.y + w2*v2.y + w3*v3.y;
  }
  for (; j < end; ++j) {
    int s0 = csr_src[j]; float w0 = iso[s0]; float2 v0 = x2[s0*64+lane];
    ax += w0*v0.x; ay += w0*v0.y;
  }
  float si = isi[wave];
  ax *= si; ay *= si;
  u16 hx,lx,hy,ly;
  split2(ax,hx,lx); split2(ay,hy,ly);
  ((int*)aggh)[wave*64+lane] = (int)hx | ((int)hy<<16);
  ((int*)aggl)[wave*64+lane] = (int)lx | ((int)ly<<16);
}

// ---------------------------------------------------------------- MFMA GEMM (split-bf16)
// C[M,Nc] = (Ahi+Alo)[M,K] @ W[K,Nc] + bias via 3 MFMAs per frag pair (hi*hi+hi*lo+lo*hi).
// W given transposed: Whi/Wlo [Nc][K]. Block 256 thr = 4 waves, tile 64x64, KC=64.
// AMODE 0: A row-major stride K. AMODE 1: row = concat(hg[row/NPG] (256), x[row] (128)), K=384.
// COUT 0: f32 C. COUT 1: bf16 pair (Chi/Clo) for chaining into the next GEMM.
#define MFMA3(ACC, AH, AL, BH, BL)                                        \
  ACC = __builtin_amdgcn_mfma_f32_16x16x32_bf16(AH, BH, ACC, 0, 0, 0);    \
  ACC = __builtin_amdgcn_mfma_f32_16x16x32_bf16(AH, BL, ACC, 0, 0, 0);    \
  ACC = __builtin_amdgcn_mfma_f32_16x16x32_bf16(AL, BH, ACC, 0, 0, 0);

template <int AMODE, int COUT>
__global__ __launch_bounds__(256) void gemm_mfma(
    const u16* __restrict__ Ahi, const u16* __restrict__ Alo,
    const u16* __restrict__ A2hi, const u16* __restrict__ A2lo,
    const u16* __restrict__ Whi, const u16* __restrict__ Wlo,
    const float* __restrict__ bias,
    float* __restrict__ C, u16* __restrict__ Chi, u16* __restrict__ Clo,
    int M, int K, int Nc, int relu) {
  // LDS rows padded +8 u16 (=16B): stride 144B -> 2-way conflict max on b128 frag reads (free)
  __shared__ u16 Ah[64 * 72], Al[64 * 72], Bh[64 * 72], Bl[64 * 72];
  int tid = threadIdx.x;
  int m0 = blockIdx.x * 64, c0 = blockIdx.y * 64;
  int lane = tid & 63, wid = tid >> 6;
  int wr = (wid >> 1) * 32, wc = (wid & 1) * 32;
  int tx = tid & 7, ty = tid >> 3;   // staging: tx = k-octet, ty = row 0..31
  int kl = tx * 8;

  floatx4 acc00 = {0.f,0.f,0.f,0.f}, acc01 = {0.f,0.f,0.f,0.f};
  floatx4 acc10 = {0.f,0.f,0.f,0.f}, acc11 = {0.f,0.f,0.f,0.f};

  for (int kb = 0; kb < K; kb += 64) {
    if (kb) __syncthreads();
    #pragma unroll
    for (int half = 0; half < 2; ++half) {
      int row = ty + half * 32;
      int kg = kb + kl;
      short8 vh = {0,0,0,0,0,0,0,0}, vl = {0,0,0,0,0,0,0,0};
      if (AMODE == 0) {
        if (kg < K) {  // K % 8 == 0 for all call sites -> whole octet in/out
          size_t base = (size_t)(m0 + row) * K + kg;
          vh = *(const short8*)&Ahi[base];
          vl = *(const short8*)&Alo[base];
        }
      } else {
        int gr = m0 + row;
        if (kg < 256) {
          size_t base = (size_t)(gr / NPG) * 256 + kg;
          vh = *(const short8*)&Ahi[base];
          vl = *(const short8*)&Alo[base];
        } else {
          size_t base = (size_t)gr * 128 + (kg - 256);
          vh = *(const short8*)&A2hi[base];
          vl = *(const short8*)&A2lo[base];
        }
      }
      *(short8*)&Ah[row * 72 + kl] = vh;
      *(short8*)&Al[row * 72 + kl] = vl;

      short8 wh = {0,0,0,0,0,0,0,0}, wl = {0,0,0,0,0,0,0,0};
      int n = c0 + row;
      if (n < Nc && kg < K) {
        size_t base = (size_t)n * K + kg;
        wh = *(const short8*)&Whi[base];
        wl = *(const short8*)&Wlo[base];
      }
      *(short8*)&Bh[row * 72 + kl] = wh;
      *(short8*)&Bl[row * 72 + kl] = wl;
    }
    __syncthreads();

    int ar = wr + (lane & 15);
    int br = wc + (lane & 15);
    int ks = (lane >> 4) * 8;
    #pragma unroll
    for (int ki = 0; ki < 2; ++ki) {
      int ko = ki * 32 + ks;
      short8 a0h = *(const short8*)&Ah[(ar     ) * 72 + ko];
      short8 a1h = *(const short8*)&Ah[(ar + 16) * 72 + ko];
      short8 a0l = *(const short8*)&Al[(ar     ) * 72 + ko];
      short8 a1l = *(const short8*)&Al[(ar + 16) * 72 + ko];
      short8 b0h = *(const short8*)&Bh[(br     ) * 72 + ko];
      short8 b1h = *(const short8*)&Bh[(br + 16) * 72 + ko];
      short8 b0l = *(const short8*)&Bl[(br     ) * 72 + ko];
      short8 b1l = *(const short8*)&Bl[(br + 16) * 72 + ko];
      MFMA3(acc00, a0h, a0l, b0h, b0l);
      MFMA3(acc01, a0h, a0l, b1h, b1l);
      MFMA3(acc10, a1h, a1l, b0h, b0l);
      MFMA3(acc11, a1h, a1l, b1h, b1l);
    }
  }

  // epilogue: C/D layout col=lane&15, row=(lane>>4)*4+r  [verified m89]
  #pragma unroll
  for (int mi = 0; mi < 2; ++mi) {
    #pragma unroll
    for (int ni = 0; ni < 2; ++ni) {
      floatx4 a = (mi == 0) ? (ni == 0 ? acc00 : acc01) : (ni == 0 ? acc10 : acc11);
      int ccol = c0 + wc + ni * 16 + (lane & 15);
      if (ccol >= Nc) continue;
      float bb = bias[ccol];
      int r0 = m0 + wr + mi * 16 + ((lane >> 4) << 2);
      #pragma unroll
      for (int r = 0; r < 4; ++r) {
        float v = a[r] + bb;
        if (relu) v = fmaxf(v, 0.f);
        size_t idx = (size_t)(r0 + r) * Nc + ccol;
        if (COUT == 0) {
          C[idx] = v;
        } else {
          u16 h, l;
          split2(v, h, l);
          Chi[idx] = h;
          Clo[idx] = l;
        }
      }
    }
  }
}

// ---------------------------------------------------------------- BN pieces
__global__ __launch_bounds__(256) void col_stats(const float* __restrict__ h,
                                                 float* __restrict__ sums) {
  __shared__ float sh[256];
  int c = threadIdx.x & 127, half = threadIdx.x >> 7;
  float s = 0.f, q = 0.f;
  for (int r = blockIdx.x * 2 + half; r < N_NODES; r += gridDim.x * 2) {
    float v = h[(size_t)r * HDIM + c];
    s += v; q += v * v;
  }
  sh[threadIdx.x] = s;
  __syncthreads();
  if (threadIdx.x < 128) atomicAdd(&sums[c], sh[threadIdx.x] + sh[threadIdx.x + 128]);
  __syncthreads();
  sh[threadIdx.x] = q;
  __syncthreads();
  if (threadIdx.x < 128) atomicAdd(&sums[128 + c], sh[threadIdx.x] + sh[threadIdx.x + 128]);
}

__global__ void bn_finalize(const float* __restrict__ sums,
                            const float* __restrict__ gamma,
                            const float* __restrict__ beta,
                            float* __restrict__ sc) {
  int c = threadIdx.x;  // 128
  float mu = sums[c] / (float)N_NODES;
  float var = sums[128 + c] / (float)N_NODES - mu * mu;
  float s = gamma[c] / sqrtf(var + 1e-5f);
  sc[c] = s;
  sc[128 + c] = beta[c] - mu * s;
}

// x += relu(h*scale + shift); optionally also emit bf16 pair of x (final layer)
__global__ __launch_bounds__(256) void bn_apply(const float* __restrict__ h,
                                                const float* __restrict__ sc,
                                                float* __restrict__ x,
                                                u16* __restrict__ xhi,
                                                u16* __restrict__ xlo) {
  const float4* h4 = (const float4*)h;
  const float4* s4 = (const float4*)sc;
  float4* x4 = (float4*)x;
  int i = blockIdx.x * 256 + threadIdx.x;
  int stride = gridDim.x * 256;
  for (; i < N_NODES * 32; i += stride) {
    int c4 = i & 31;
    float4 hv = h4[i];
    float4 sv = s4[c4];
    float4 bv = s4[32 + c4];
    float4 xv = x4[i];
    xv.x += fmaxf(hv.x * sv.x + bv.x, 0.f);
    xv.y += fmaxf(hv.y * sv.y + bv.y, 0.f);
    xv.z += fmaxf(hv.z * sv.z + bv.z, 0.f);
    xv.w += fmaxf(hv.w * sv.w + bv.w, 0.f);
    x4[i] = xv;
    if (xhi) {
      u16 h0,l0,h1,l1,h2,l2,h3,l3;
      split2(xv.x,h0,l0); split2(xv.y,h1,l1); split2(xv.z,h2,l2); split2(xv.w,h3,l3);
      ((int2*)xhi)[i] = make_int2((int)h0 | ((int)h1<<16), (int)h2 | ((int)h3<<16));
      ((int2*)xlo)[i] = make_int2((int)l0 | ((int)l1<<16), (int)l2 | ((int)l3<<16));
    }
  }
}

// ---------------------------------------------------------------- pooling / labels
__global__ __launch_bounds__(256) void pool_kernel(const float* __restrict__ x,
                                                   u16* __restrict__ hg_h,
                                                   u16* __restrict__ hg_l) {
  __shared__ float sh[512];
  int b = blockIdx.x;
  int c = threadIdx.x & 127, half = threadIdx.x >> 7;
  const float* xb = x + (size_t)b * NPG * HDIM;
  float s = 0.f, m = -3.4e38f;
  for (int r = half; r < NPG; r += 2) {
    float v = xb[(size_t)r * HDIM + c];
    s += v;
    m = fmaxf(m, v);
  }
  sh[threadIdx.x] = s;
  sh[256 + threadIdx.x] = m;
  __syncthreads();
  if (threadIdx.x < 128) {
    float avg = (sh[threadIdx.x] + sh[128 + threadIdx.x]) / (float)NPG;
    float mx  = fmaxf(sh[256 + threadIdx.x], sh[384 + threadIdx.x]);
    u16 h, l;
    split2(avg, h, l); hg_h[b * 256 + c] = h;       hg_l[b * 256 + c] = l;
    split2(mx,  h, l); hg_h[b * 256 + 128 + c] = h; hg_l[b * 256 + 128 + c] = l;
  }
}

__global__ __launch_bounds__(256) void label_kernel(const int* __restrict__ labels,
                                                    float* __restrict__ out) {
  int i = blockIdx.x * 256 + threadIdx.x;
  if (i < N_NODES) out[i] = (float)labels[i / NPG];
}

// ---------------------------------------------------------------- launch
extern "C" void kernel_launch(void* const* d_in, const int* in_sizes, int n_in,
                              void* d_out, int out_size, void* d_ws, size_t ws_size,
                              hipStream_t stream) {
  const float* feature  = (const float*)d_in[0];
  const int*   esrc     = (const int*)d_in[1];
  const int*   edst     = (const int*)d_in[2];
  const int*   labels   = (const int*)d_in[3];
  const float* W_emb    = (const float*)d_in[4];
  const float* b_emb    = (const float*)d_in[5];
  const float* gcn_W    = (const float*)d_in[6];
  const float* gcn_b    = (const float*)d_in[7];
  const float* gcn_g    = (const float*)d_in[8];
  const float* gcn_be   = (const float*)d_in[9];
  const float* gW1 = (const float*)d_in[10];
  const float* gb1 = (const float*)d_in[11];
  const float* gW2 = (const float*)d_in[12];
  const float* gb2 = (const float*)d_in[13];
  const float* gW3 = (const float*)d_in[14];
  const float* gb3 = (const float*)d_in[15];
  const float* nW1 = (const float*)d_in[16];
  const float* nb1 = (const float*)d_in[17];
  const float* nW2 = (const float*)d_in[18];
  const float* nb2 = (const float*)d_in[19];
  const float* nW3 = (const float*)d_in[20];
  const float* nb3 = (const float*)d_in[21];

  // output layout: x [N,128] | x_g [N,10] | g [128,10] | node_label [N]
  float* x     = (float*)d_out;
  float* outXG = x + (size_t)N_NODES * HDIM;
  float* outG  = outXG + (size_t)N_NODES * CDIM;
  float* outLb = outG + NGRAPH * CDIM;

  // ---- workspace layout (bytes). Peak 131,560,192 B — PROVEN to fit:
  // round-2 run passed using 137,163,520 B of ws.
  // Lifetime aliasing:
  //   csr_src dead after last agg;  f pair dead after emb GEMM;
  //   h dead after last bn_apply    => t1 (76.9 MB) overlays {csr_src, f, h}.
  //   agg pair dead when its GEMM completes; x pair dead after node-head GEMM1
  //                                 => {agg, x, t2} share region RB.
  char* ws = (char*)d_ws;
  float* iso     = (float*)(ws + 0);
  float* isi     = (float*)(ws + 400384);
  int*   cnt_src = (int*)  (ws + 800768);
  int*   cnt_dst = (int*)  (ws + 1201152);
  int*   pos     = (int*)  (ws + 1601536);
  int*   csr_off = (int*)  (ws + 2001920);
  int*   bsum    = (int*)  (ws + 2402560);
  float* bnsum   = (float*)(ws + 2403072);
  float* bnsc    = (float*)(ws + 2404096);
  u16*   hg_h    = (u16*)  (ws + 2405120);   // [128][256]
  u16*   hg_l    = (u16*)  (ws + 2470656);
  u16*   g1_h    = (u16*)  (ws + 2536192);   // [128][128]
  u16*   g1_l    = (u16*)  (ws + 2568960);
  u16*   g2_h    = (u16*)  (ws + 2601728);   // [128][64]
  u16*   g2_l    = (u16*)  (ws + 2618112);
  // transposed split weights [Nc][K]
  u16* embt_h = (u16*)(ws + 2634496);        // [128][128]
  u16* embt_l = (u16*)(ws + 2667264);
  u16* gcnt_h = (u16*)(ws + 2700032);        // 3 x [128][128]
  u16* gcnt_l = (u16*)(ws + 2798336);
  u16* g1t_h  = (u16*)(ws + 2896640);        // [128][256]
  u16* g1t_l  = (u16*)(ws + 2962176);
  u16* g2t_h  = (u16*)(ws + 3027712);        // [64][128]
  u16* g2t_l  = (u16*)(ws + 3044096);
  u16* g3t_h  = (u16*)(ws + 3060480);        // [10][64]
  u16* g3t_l  = (u16*)(ws + 3062528);
  u16* n1t_h  = (u16*)(ws + 3064576);        // [192][384]
  u16* n1t_l  = (u16*)(ws + 3212032);
  u16* n2t_h  = (u16*)(ws + 3359488);        // [96][192]
  u16* n2t_l  = (u16*)(ws + 3396352);
  u16* n3t_h  = (u16*)(ws + 3433216);        // [10][96]
  u16* n3t_l  = (u16*)(ws + 3435264);
  // csr_src: 3,437,312 .. 9,843,456 (dead after last agg)
  int*   csr_src = (int*)(ws + 3437312);     // E ints
  // RA: f pair / h (f32)  : 9,843,456 .. 61,092,608
  u16*   f_h  = (u16*)  (ws + 9843456);
  u16*   f_l  = (u16*)  (ws + 35468032);
  float* h    = (float*)(ws + 9843456);
  // t1 pair overlays {csr_src, f, h}: 3,437,312 .. 80,311,040
  u16*   t1_h = (u16*)(ws + 3437312);
  u16*   t1_l = (u16*)(ws + 41874176);
  // RB: agg pair -> x pair -> t2 pair : 80,311,040 .. 131,560,192
  u16*   agg_h = (u16*)(ws + 80311040);
  u16*   agg_l = (u16*)(ws + 105935616);
  u16*   x_h   = (u16*)(ws + 80311040);
  u16*   x_l   = (u16*)(ws + 105935616);
  u16*   t2_h  = (u16*)(ws + 80311040);
  u16*   t2_l  = (u16*)(ws + 99529472);

  // ---- degrees + CSR build
  hipMemsetAsync(cnt_src, 0, (size_t)N_NODES * 4, stream);
  hipMemsetAsync(cnt_dst, 0, (size_t)N_NODES * 4, stream);
  hipMemsetAsync(pos,     0, (size_t)N_NODES * 4, stream);
  deg_kernel<<<2048, 256, 0, stream>>>(esrc, edst, cnt_src, cnt_dst);
  inv_kernel<<<(N_NODES + 255) / 256, 256, 0, stream>>>(cnt_src, cnt_dst, iso, isi);
  scan1_kernel<<<98, 256, 0, stream>>>(cnt_dst, csr_off, bsum);
  scan2_kernel<<<1, 1, 0, stream>>>(bsum, 98);
  scan3_kernel<<<98, 256, 0, stream>>>(csr_off, bsum);
  scatter_kernel<<<2048, 256, 0, stream>>>(esrc, edst, csr_off, pos, csr_src);

  // ---- weight + feature splits
  wsplit<<<64, 256, 0, stream>>>(W_emb, embt_h, embt_l, 128, 128);
  for (int l = 0; l < 3; ++l)
    wsplit<<<64, 256, 0, stream>>>(gcn_W + (size_t)l * 16384,
                                   gcnt_h + (size_t)l * 16384,
                                   gcnt_l + (size_t)l * 16384, 128, 128);
  wsplit<<<128, 256, 0, stream>>>(gW1, g1t_h, g1t_l, 256, 128);
  wsplit<<<32, 256, 0, stream>>>(gW2, g2t_h, g2t_l, 128, 64);
  wsplit<<<3, 256, 0, stream>>>(gW3, g3t_h, g3t_l, 64, 10);
  wsplit<<<288, 256, 0, stream>>>(nW1, n1t_h, n1t_l, 384, 192);
  wsplit<<<72, 256, 0, stream>>>(nW2, n2t_h, n2t_l, 192, 96);
  wsplit<<<4, 256, 0, stream>>>(nW3, n3t_h, n3t_l, 96, 10);
  split_pair<<<12512, 256, 0, stream>>>(feature, f_h, f_l, N_NODES * 32);

  // ---- embedding: x = feature @ W_emb + b_emb
  gemm_mfma<0,0><<<dim3(1564, 2), 256, 0, stream>>>(f_h, f_l, nullptr, nullptr,
                                                    embt_h, embt_l, b_emb,
                                                    x, nullptr, nullptr,
                                                    N_NODES, 128, 128, 0);

  // ---- GCN layers
  for (int l = 0; l < 3; ++l) {
    hipMemsetAsync(bnsum, 0, 1024, stream);
    agg_kernel<<<N_NODES / 4, 256, 0, stream>>>(x, csr_off, csr_src, iso, isi, agg_h, agg_l);
    gemm_mfma<0,0><<<dim3(1564, 2), 256, 0, stream>>>(agg_h, agg_l, nullptr, nullptr,
                                                      gcnt_h + (size_t)l * 16384,
                                                      gcnt_l + (size_t)l * 16384,
                                                      gcn_b + l * 128,
                                                      h, nullptr, nullptr,
                                                      N_NODES, 128, 128, 0);
    col_stats<<<512, 256, 0, stream>>>(h, bnsum);
    bn_finalize<<<1, 128, 0, stream>>>(bnsum, gcn_g + l * 128, gcn_be + l * 128, bnsc);
    bn_apply<<<2048, 256, 0, stream>>>(h, bnsc, x,
                                       (l == 2) ? x_h : nullptr,
                                       (l == 2) ? x_l : nullptr);
  }

  // ---- pooling (emits bf16 pair hg)
  pool_kernel<<<NGRAPH, 256, 0, stream>>>(x, hg_h, hg_l);

  // ---- graph head: 256 -> 128 -> 64 -> 10
  gemm_mfma<0,1><<<dim3(2, 2), 256, 0, stream>>>(hg_h, hg_l, nullptr, nullptr,
                                                 g1t_h, g1t_l, gb1,
                                                 nullptr, g1_h, g1_l, NGRAPH, 256, 128, 1);
  gemm_mfma<0,1><<<dim3(2, 1), 256, 0, stream>>>(g1_h, g1_l, nullptr, nullptr,
                                                 g2t_h, g2t_l, gb2,
                                                 nullptr, g2_h, g2_l, NGRAPH, 128, 64, 1);
  gemm_mfma<0,0><<<dim3(2, 1), 256, 0, stream>>>(g2_h, g2_l, nullptr, nullptr,
                                                 g3t_h, g3t_l, gb3,
                                                 outG, nullptr, nullptr, NGRAPH, 64, 10, 0);

  // ---- node head: concat(hg[seg], x) [N,384] -> 192 -> 96 -> 10
  gemm_mfma<1,1><<<dim3(1564, 3), 256, 0, stream>>>(hg_h, hg_l, x_h, x_l,
                                                    n1t_h, n1t_l, nb1,
                                                    nullptr, t1_h, t1_l, N_NODES, 384, 192, 1);
  gemm_mfma<0,1><<<dim3(1564, 2), 256, 0, stream>>>(t1_h, t1_l, nullptr, nullptr,
                                                    n2t_h, n2t_l, nb2,
                                                    nullptr, t2_h, t2_l, N_NODES, 192, 96, 1);
  gemm_mfma<0,0><<<dim3(1564, 1), 256, 0, stream>>>(t2_h, t2_l, nullptr, nullptr,
                                                    n3t_h, n3t_l, nb3,
                                                    outXG, nullptr, nullptr, N_NODES, 96, 10, 0);

  // ---- node labels
  label_kernel<<<(N_NODES + 255) / 256, 256, 0, stream>>>(labels, outLb);
}

// Round 7
// 1282.523 us; speedup vs baseline: 2.1401x; 1.0624x over previous
//
#include <hip/hip_runtime.h>

#define N_NODES 100096
#define N_EDGES 1601536
#define NGRAPH  128
#define NPG     782
#define HDIM    128
#define CDIM    10

typedef unsigned short u16;
typedef short short8 __attribute__((ext_vector_type(8)));
typedef float floatx4 __attribute__((ext_vector_type(4)));

// ---- bf16 split helpers (RNE) : f ~= hi + lo, |err| ~ 2^-16 |f|
__device__ __forceinline__ u16 bfh(float f) {
  unsigned u = __float_as_uint(f);
  u += 0x7FFFu + ((u >> 16) & 1u);
  return (u16)(u >> 16);
}
__device__ __forceinline__ float bff(u16 h) {
  return __uint_as_float(((unsigned)h) << 16);
}
__device__ __forceinline__ void split2(float f, u16& hi, u16& lo) {
  hi = bfh(f);
  lo = bfh(f - bff(hi));
}

// ---------------------------------------------------------------- degree / CSR
// Split histograms: each ~63 us (atomic write-through bound: 32B/op to HBM,
// measured r6: 99.9MB WRITE for 3.2M atomics). Split gives profiling visibility
// below the 126us single-kernel ceiling. deg_dst also records each edge's
// within-segment rank (free from the atomic return) -> scatter needs no atomics.
__global__ __launch_bounds__(256) void deg_src_kernel(const int* __restrict__ src,
                                                      int* __restrict__ cnt_src) {
  int i = blockIdx.x * 256 + threadIdx.x;
  int stride = gridDim.x * 256;
  for (; i < N_EDGES; i += stride) atomicAdd(&cnt_src[src[i]], 1);
}

__global__ __launch_bounds__(256) void deg_dst_kernel(const int* __restrict__ dst,
                                                      int* __restrict__ cnt_dst,
                                                      int* __restrict__ rank) {
  int i = blockIdx.x * 256 + threadIdx.x;
  int stride = gridDim.x * 256;
  for (; i < N_EDGES; i += stride) rank[i] = atomicAdd(&cnt_dst[dst[i]], 1);
}

__global__ __launch_bounds__(256) void inv_kernel(const int* __restrict__ cs,
                                                  const int* __restrict__ cd,
                                                  float* __restrict__ iso,
                                                  float* __restrict__ isi) {
  int i = blockIdx.x * 256 + threadIdx.x;
  if (i < N_NODES) {
    int a = cs[i] > 1 ? cs[i] : 1;
    int b = cd[i] > 1 ? cd[i] : 1;
    iso[i] = 1.0f / sqrtf((float)a);
    isi[i] = 1.0f / sqrtf((float)b);
  }
}

__global__ __launch_bounds__(256) void scan1_kernel(const int* __restrict__ cnt,
                                                    int* __restrict__ out,
                                                    int* __restrict__ bsum) {
  __shared__ int sh[256];
  int tid = threadIdx.x;
  int base = blockIdx.x * 1024 + tid * 4;
  int v[4]; int tsum = 0;
  #pragma unroll
  for (int t = 0; t < 4; t++) { int idx = base + t; v[t] = (idx < N_NODES) ? cnt[idx] : 0; tsum += v[t]; }
  sh[tid] = tsum;
  for (int off = 1; off < 256; off <<= 1) {
    __syncthreads();
    int add = (tid >= off) ? sh[tid - off] : 0;
    __syncthreads();
    sh[tid] += add;
  }
  __syncthreads();
  int excl = sh[tid] - tsum;
  #pragma unroll
  for (int t = 0; t < 4; t++) { int idx = base + t; if (idx < N_NODES) out[idx] = excl; excl += v[t]; }
  if (tid == 255) bsum[blockIdx.x] = sh[255];
}

__global__ void scan2_kernel(int* __restrict__ bsum, int nb) {
  if (blockIdx.x == 0 && threadIdx.x == 0) {
    int run = 0;
    for (int i = 0; i < nb; i++) { int t = bsum[i]; bsum[i] = run; run += t; }
  }
}

__global__ __launch_bounds__(256) void scan3_kernel(int* __restrict__ out,
                                                    const int* __restrict__ bsum) {
  int add = bsum[blockIdx.x];
  int base = blockIdx.x * 1024 + threadIdx.x * 4;
  #pragma unroll
  for (int t = 0; t < 4; t++) { int idx = base + t; if (idx < N_NODES) out[idx] += add; }
  if (blockIdx.x == 0 && threadIdx.x == 0) out[N_NODES] = N_EDGES;
}

// atomic-free scatter: slot = csr_off[dst] + rank (rank from deg_dst's atomic return)
__global__ __launch_bounds__(256) void scatter_kernel(const int* __restrict__ src,
                                                      const int* __restrict__ dst,
                                                      const int* __restrict__ off,
                                                      const int* __restrict__ rank,
                                                      int* __restrict__ csr_src) {
  int i = blockIdx.x * 256 + threadIdx.x;
  for (; i < N_EDGES; i += gridDim.x * 256) {
    csr_src[off[dst[i]] + rank[i]] = src[i];
  }
}

// ---------------------------------------------------------------- splits
// f32 -> (hi,lo) bf16 pair, vectorized by 4
__global__ __launch_bounds__(256) void split_pair(const float* __restrict__ in,
                                                  u16* __restrict__ hi,
                                                  u16* __restrict__ lo, int n4) {
  int i = blockIdx.x * 256 + threadIdx.x;
  if (i >= n4) return;
  float4 v = ((const float4*)in)[i];
  u16 h0,l0,h1,l1,h2,l2,h3,l3;
  split2(v.x,h0,l0); split2(v.y,h1,l1); split2(v.z,h2,l2); split2(v.w,h3,l3);
  int2 ph = make_int2((int)h0 | ((int)h1<<16), (int)h2 | ((int)h3<<16));
  int2 pl = make_int2((int)l0 | ((int)l1<<16), (int)l2 | ((int)l3<<16));
  ((int2*)hi)[i] = ph;
  ((int2*)lo)[i] = pl;
}

// W [K][Nc] f32 -> Wt_hi/Wt_lo [Nc][K] bf16 (transposed for MFMA B staging)
__global__ __launch_bounds__(256) void wsplit(const float* __restrict__ W,
                                              u16* __restrict__ Thi,
                                              u16* __restrict__ Tlo, int K, int Nc) {
  int i = blockIdx.x * 256 + threadIdx.x;
  if (i >= K * Nc) return;
  int k = i / Nc, n = i - k * Nc;
  u16 h, l;
  split2(W[i], h, l);
  Thi[n * K + k] = h;
  Tlo[n * K + k] = l;
}

// ---------------------------------------------------------------- aggregation
// one wave per dst node; lane holds channels [2*lane, 2*lane+1]; unroll-4 for latency.
// Writes bf16 hi/lo pair (feeds MFMA GEMM directly; same bytes as f32).
__global__ __launch_bounds__(256) void agg_kernel(const float* __restrict__ x,
                                                  const int* __restrict__ off,
                                                  const int* __restrict__ csr_src,
                                                  const float* __restrict__ iso,
                                                  const float* __restrict__ isi,
                                                  u16* __restrict__ aggh,
                                                  u16* __restrict__ aggl) {
  int wave = (blockIdx.x * 256 + threadIdx.x) >> 6;
  int lane = threadIdx.x & 63;
  if (wave >= N_NODES) return;
  const float2* x2 = (const float2*)x;
  int beg = off[wave], end = off[wave + 1];
  float ax = 0.f, ay = 0.f;
  int j = beg;
  for (; j + 3 < end; j += 4) {
    int s0 = csr_src[j], s1 = csr_src[j+1], s2 = csr_src[j+2], s3 = csr_src[j+3];
    float w0 = iso[s0], w1 = iso[s1], w2 = iso[s2], w3 = iso[s3];
    float2 v0 = x2[s0*64+lane], v1 = x2[s1*64+lane], v2 = x2[s2*64+lane], v3 = x2[s3*64+lane];
    ax += w0*v0.x + w1*v1.x + w2*v2.x + w3*v3.x;
    ay += w0*v0.y + w1*v1.y + w2*v2.y + w3*v3.y;
  }
  for (; j < end; ++j) {
    int s0 = csr_src[j]; float w0 = iso[s0]; float2 v0 = x2[s0*64+lane];
    ax += w0*v0.x; ay += w0*v0.y;
  }
  float si = isi[wave];
  ax *= si; ay *= si;
  u16 hx,lx,hy,ly;
  split2(ax,hx,lx); split2(ay,hy,ly);
  ((int*)aggh)[wave*64+lane] = (int)hx | ((int)hy<<16);
  ((int*)aggl)[wave*64+lane] = (int)lx | ((int)ly<<16);
}

// ---------------------------------------------------------------- MFMA GEMM (split-bf16)
// C[M,Nc] = (Ahi+Alo)[M,K] @ W[K,Nc] + bias via 3 MFMAs per frag pair (hi*hi+hi*lo+lo*hi).
// W given transposed: Whi/Wlo [Nc][K]. Block 256 thr = 4 waves, tile 64x64, KC=64.
// AMODE 0: A row-major stride K. AMODE 1: row = concat(hg[row/NPG] (256), x[row] (128)), K=384.
// COUT 0: f32 C. COUT 1: bf16 pair (Chi/Clo) for chaining into the next GEMM.
#define MFMA3(ACC, AH, AL, BH, BL)                                        \
  ACC = __builtin_amdgcn_mfma_f32_16x16x32_bf16(AH, BH, ACC, 0, 0, 0);    \
  ACC = __builtin_amdgcn_mfma_f32_16x16x32_bf16(AH, BL, ACC, 0, 0, 0);    \
  ACC = __builtin_amdgcn_mfma_f32_16x16x32_bf16(AL, BH, ACC, 0, 0, 0);

template <int AMODE, int COUT>
__global__ __launch_bounds__(256) void gemm_mfma(
    const u16* __restrict__ Ahi, const u16* __restrict__ Alo,
    const u16* __restrict__ A2hi, const u16* __restrict__ A2lo,
    const u16* __restrict__ Whi, const u16* __restrict__ Wlo,
    const float* __restrict__ bias,
    float* __restrict__ C, u16* __restrict__ Chi, u16* __restrict__ Clo,
    int M, int K, int Nc, int relu) {
  // LDS rows padded +8 u16 (=16B): stride 144B -> 2-way conflict max on b128 frag reads (free)
  __shared__ u16 Ah[64 * 72], Al[64 * 72], Bh[64 * 72], Bl[64 * 72];
  int tid = threadIdx.x;
  int m0 = blockIdx.x * 64, c0 = blockIdx.y * 64;
  int lane = tid & 63, wid = tid >> 6;
  int wr = (wid >> 1) * 32, wc = (wid & 1) * 32;
  int tx = tid & 7, ty = tid >> 3;   // staging: tx = k-octet, ty = row 0..31
  int kl = tx * 8;

  floatx4 acc00 = {0.f,0.f,0.f,0.f}, acc01 = {0.f,0.f,0.f,0.f};
  floatx4 acc10 = {0.f,0.f,0.f,0.f}, acc11 = {0.f,0.f,0.f,0.f};

  for (int kb = 0; kb < K; kb += 64) {
    if (kb) __syncthreads();
    #pragma unroll
    for (int half = 0; half < 2; ++half) {
      int row = ty + half * 32;
      int kg = kb + kl;
      short8 vh = {0,0,0,0,0,0,0,0}, vl = {0,0,0,0,0,0,0,0};
      if (AMODE == 0) {
        if (kg < K) {  // K % 8 == 0 for all call sites -> whole octet in/out
          size_t base = (size_t)(m0 + row) * K + kg;
          vh = *(const short8*)&Ahi[base];
          vl = *(const short8*)&Alo[base];
        }
      } else {
        int gr = m0 + row;
        if (kg < 256) {
          size_t base = (size_t)(gr / NPG) * 256 + kg;
          vh = *(const short8*)&Ahi[base];
          vl = *(const short8*)&Alo[base];
        } else {
          size_t base = (size_t)gr * 128 + (kg - 256);
          vh = *(const short8*)&A2hi[base];
          vl = *(const short8*)&A2lo[base];
        }
      }
      *(short8*)&Ah[row * 72 + kl] = vh;
      *(short8*)&Al[row * 72 + kl] = vl;

      short8 wh = {0,0,0,0,0,0,0,0}, wl = {0,0,0,0,0,0,0,0};
      int n = c0 + row;
      if (n < Nc && kg < K) {
        size_t base = (size_t)n * K + kg;
        wh = *(const short8*)&Whi[base];
        wl = *(const short8*)&Wlo[base];
      }
      *(short8*)&Bh[row * 72 + kl] = wh;
      *(short8*)&Bl[row * 72 + kl] = wl;
    }
    __syncthreads();

    int ar = wr + (lane & 15);
    int br = wc + (lane & 15);
    int ks = (lane >> 4) * 8;
    #pragma unroll
    for (int ki = 0; ki < 2; ++ki) {
      int ko = ki * 32 + ks;
      short8 a0h = *(const short8*)&Ah[(ar     ) * 72 + ko];
      short8 a1h = *(const short8*)&Ah[(ar + 16) * 72 + ko];
      short8 a0l = *(const short8*)&Al[(ar     ) * 72 + ko];
      short8 a1l = *(const short8*)&Al[(ar + 16) * 72 + ko];
      short8 b0h = *(const short8*)&Bh[(br     ) * 72 + ko];
      short8 b1h = *(const short8*)&Bh[(br + 16) * 72 + ko];
      short8 b0l = *(const short8*)&Bl[(br     ) * 72 + ko];
      short8 b1l = *(const short8*)&Bl[(br + 16) * 72 + ko];
      MFMA3(acc00, a0h, a0l, b0h, b0l);
      MFMA3(acc01, a0h, a0l, b1h, b1l);
      MFMA3(acc10, a1h, a1l, b0h, b0l);
      MFMA3(acc11, a1h, a1l, b1h, b1l);
    }
  }

  // epilogue: C/D layout col=lane&15, row=(lane>>4)*4+r  [verified m89]
  #pragma unroll
  for (int mi = 0; mi < 2; ++mi) {
    #pragma unroll
    for (int ni = 0; ni < 2; ++ni) {
      floatx4 a = (mi == 0) ? (ni == 0 ? acc00 : acc01) : (ni == 0 ? acc10 : acc11);
      int ccol = c0 + wc + ni * 16 + (lane & 15);
      if (ccol >= Nc) continue;
      float bb = bias[ccol];
      int r0 = m0 + wr + mi * 16 + ((lane >> 4) << 2);
      #pragma unroll
      for (int r = 0; r < 4; ++r) {
        float v = a[r] + bb;
        if (relu) v = fmaxf(v, 0.f);
        size_t idx = (size_t)(r0 + r) * Nc + ccol;
        if (COUT == 0) {
          C[idx] = v;
        } else {
          u16 h, l;
          split2(v, h, l);
          Chi[idx] = h;
          Clo[idx] = l;
        }
      }
    }
  }
}

// ---------------------------------------------------------------- BN pieces
__global__ __launch_bounds__(256) void col_stats(const float* __restrict__ h,
                                                 float* __restrict__ sums) {
  __shared__ float sh[256];
  int c = threadIdx.x & 127, half = threadIdx.x >> 7;
  float s = 0.f, q = 0.f;
  for (int r = blockIdx.x * 2 + half; r < N_NODES; r += gridDim.x * 2) {
    float v = h[(size_t)r * HDIM + c];
    s += v; q += v * v;
  }
  sh[threadIdx.x] = s;
  __syncthreads();
  if (threadIdx.x < 128) atomicAdd(&sums[c], sh[threadIdx.x] + sh[threadIdx.x + 128]);
  __syncthreads();
  sh[threadIdx.x] = q;
  __syncthreads();
  if (threadIdx.x < 128) atomicAdd(&sums[128 + c], sh[threadIdx.x] + sh[threadIdx.x + 128]);
}

__global__ void bn_finalize(const float* __restrict__ sums,
                            const float* __restrict__ gamma,
                            const float* __restrict__ beta,
                            float* __restrict__ sc) {
  int c = threadIdx.x;  // 128
  float mu = sums[c] / (float)N_NODES;
  float var = sums[128 + c] / (float)N_NODES - mu * mu;
  float s = gamma[c] / sqrtf(var + 1e-5f);
  sc[c] = s;
  sc[128 + c] = beta[c] - mu * s;
}

// x += relu(h*scale + shift); optionally also emit bf16 pair of x (final layer)
__global__ __launch_bounds__(256) void bn_apply(const float* __restrict__ h,
                                                const float* __restrict__ sc,
                                                float* __restrict__ x,
                                                u16* __restrict__ xhi,
                                                u16* __restrict__ xlo) {
  const float4* h4 = (const float4*)h;
  const float4* s4 = (const float4*)sc;
  float4* x4 = (float4*)x;
  int i = blockIdx.x * 256 + threadIdx.x;
  int stride = gridDim.x * 256;
  for (; i < N_NODES * 32; i += stride) {
    int c4 = i & 31;
    float4 hv = h4[i];
    float4 sv = s4[c4];
    float4 bv = s4[32 + c4];
    float4 xv = x4[i];
    xv.x += fmaxf(hv.x * sv.x + bv.x, 0.f);
    xv.y += fmaxf(hv.y * sv.y + bv.y, 0.f);
    xv.z += fmaxf(hv.z * sv.z + bv.z, 0.f);
    xv.w += fmaxf(hv.w * sv.w + bv.w, 0.f);
    x4[i] = xv;
    if (xhi) {
      u16 h0,l0,h1,l1,h2,l2,h3,l3;
      split2(xv.x,h0,l0); split2(xv.y,h1,l1); split2(xv.z,h2,l2); split2(xv.w,h3,l3);
      ((int2*)xhi)[i] = make_int2((int)h0 | ((int)h1<<16), (int)h2 | ((int)h3<<16));
      ((int2*)xlo)[i] = make_int2((int)l0 | ((int)l1<<16), (int)l2 | ((int)l3<<16));
    }
  }
}

// ---------------------------------------------------------------- pooling / labels
__global__ __launch_bounds__(256) void pool_kernel(const float* __restrict__ x,
                                                   u16* __restrict__ hg_h,
                                                   u16* __restrict__ hg_l) {
  __shared__ float sh[512];
  int b = blockIdx.x;
  int c = threadIdx.x & 127, half = threadIdx.x >> 7;
  const float* xb = x + (size_t)b * NPG * HDIM;
  float s = 0.f, m = -3.4e38f;
  for (int r = half; r < NPG; r += 2) {
    float v = xb[(size_t)r * HDIM + c];
    s += v;
    m = fmaxf(m, v);
  }
  sh[threadIdx.x] = s;
  sh[256 + threadIdx.x] = m;
  __syncthreads();
  if (threadIdx.x < 128) {
    float avg = (sh[threadIdx.x] + sh[128 + threadIdx.x]) / (float)NPG;
    float mx  = fmaxf(sh[256 + threadIdx.x], sh[384 + threadIdx.x]);
    u16 h, l;
    split2(avg, h, l); hg_h[b * 256 + c] = h;       hg_l[b * 256 + c] = l;
    split2(mx,  h, l); hg_h[b * 256 + 128 + c] = h; hg_l[b * 256 + 128 + c] = l;
  }
}

__global__ __launch_bounds__(256) void label_kernel(const int* __restrict__ labels,
                                                    float* __restrict__ out) {
  int i = blockIdx.x * 256 + threadIdx.x;
  if (i < N_NODES) out[i] = (float)labels[i / NPG];
}

// ---------------------------------------------------------------- launch
extern "C" void kernel_launch(void* const* d_in, const int* in_sizes, int n_in,
                              void* d_out, int out_size, void* d_ws, size_t ws_size,
                              hipStream_t stream) {
  const float* feature  = (const float*)d_in[0];
  const int*   esrc     = (const int*)d_in[1];
  const int*   edst     = (const int*)d_in[2];
  const int*   labels   = (const int*)d_in[3];
  const float* W_emb    = (const float*)d_in[4];
  const float* b_emb    = (const float*)d_in[5];
  const float* gcn_W    = (const float*)d_in[6];
  const float* gcn_b    = (const float*)d_in[7];
  const float* gcn_g    = (const float*)d_in[8];
  const float* gcn_be   = (const float*)d_in[9];
  const float* gW1 = (const float*)d_in[10];
  const float* gb1 = (const float*)d_in[11];
  const float* gW2 = (const float*)d_in[12];
  const float* gb2 = (const float*)d_in[13];
  const float* gW3 = (const float*)d_in[14];
  const float* gb3 = (const float*)d_in[15];
  const float* nW1 = (const float*)d_in[16];
  const float* nb1 = (const float*)d_in[17];
  const float* nW2 = (const float*)d_in[18];
  const float* nb2 = (const float*)d_in[19];
  const float* nW3 = (const float*)d_in[20];
  const float* nb3 = (const float*)d_in[21];

  // output layout: x [N,128] | x_g [N,10] | g [128,10] | node_label [N]
  float* x     = (float*)d_out;
  float* outXG = x + (size_t)N_NODES * HDIM;
  float* outG  = outXG + (size_t)N_NODES * CDIM;
  float* outLb = outG + NGRAPH * CDIM;

  // ---- workspace layout (bytes). Peak 131,560,192 B — fits (r2 proved >=137.16MB).
  // Lifetime aliasing:
  //   csr_src dead after last agg;  f pair dead after emb GEMM;
  //   h dead after last bn_apply    => t1 (76.9 MB) overlays {csr_src, f, h}.
  //   rank (6.4MB) lives deg_dst->scatter, overlays RB head (agg written later).
  //   agg pair dead when its GEMM completes; x pair dead after node-head GEMM1
  //                                 => {rank, agg, x, t2} share region RB.
  char* ws = (char*)d_ws;
  float* iso     = (float*)(ws + 0);
  float* isi     = (float*)(ws + 400384);
  int*   cnt_src = (int*)  (ws + 800768);
  int*   cnt_dst = (int*)  (ws + 1201152);
  int*   csr_off = (int*)  (ws + 2001920);
  int*   bsum    = (int*)  (ws + 2402560);
  float* bnsum   = (float*)(ws + 2403072);
  float* bnsc    = (float*)(ws + 2404096);
  u16*   hg_h    = (u16*)  (ws + 2405120);   // [128][256]
  u16*   hg_l    = (u16*)  (ws + 2470656);
  u16*   g1_h    = (u16*)  (ws + 2536192);   // [128][128]
  u16*   g1_l    = (u16*)  (ws + 2568960);
  u16*   g2_h    = (u16*)  (ws + 2601728);   // [128][64]
  u16*   g2_l    = (u16*)  (ws + 2618112);
  // transposed split weights [Nc][K]
  u16* embt_h = (u16*)(ws + 2634496);        // [128][128]
  u16* embt_l = (u16*)(ws + 2667264);
  u16* gcnt_h = (u16*)(ws + 2700032);        // 3 x [128][128]
  u16* gcnt_l = (u16*)(ws + 2798336);
  u16* g1t_h  = (u16*)(ws + 2896640);        // [128][256]
  u16* g1t_l  = (u16*)(ws + 2962176);
  u16* g2t_h  = (u16*)(ws + 3027712);        // [64][128]
  u16* g2t_l  = (u16*)(ws + 3044096);
  u16* g3t_h  = (u16*)(ws + 3060480);        // [10][64]
  u16* g3t_l  = (u16*)(ws + 3062528);
  u16* n1t_h  = (u16*)(ws + 3064576);        // [192][384]
  u16* n1t_l  = (u16*)(ws + 3212032);
  u16* n2t_h  = (u16*)(ws + 3359488);        // [96][192]
  u16* n2t_l  = (u16*)(ws + 3396352);
  u16* n3t_h  = (u16*)(ws + 3433216);        // [10][96]
  u16* n3t_l  = (u16*)(ws + 3435264);
  // csr_src: 3,437,312 .. 9,843,456 (dead after last agg)
  int*   csr_src = (int*)(ws + 3437312);     // E ints
  // RA: f pair / h (f32)  : 9,843,456 .. 61,092,608
  u16*   f_h  = (u16*)  (ws + 9843456);
  u16*   f_l  = (u16*)  (ws + 35468032);
  float* h    = (float*)(ws + 9843456);
  // t1 pair overlays {csr_src, f, h}: 3,437,312 .. 80,311,040
  u16*   t1_h = (u16*)(ws + 3437312);
  u16*   t1_l = (u16*)(ws + 41874176);
  // RB: rank -> agg pair -> x pair -> t2 pair : 80,311,040 .. 131,560,192
  int*   rank  = (int*)(ws + 80311040);      // E ints (deg_dst -> scatter)
  u16*   agg_h = (u16*)(ws + 80311040);
  u16*   agg_l = (u16*)(ws + 105935616);
  u16*   x_h   = (u16*)(ws + 80311040);
  u16*   x_l   = (u16*)(ws + 105935616);
  u16*   t2_h  = (u16*)(ws + 80311040);
  u16*   t2_l  = (u16*)(ws + 99529472);

  // ---- degrees + CSR build (rank trick: scatter is atomic-free)
  hipMemsetAsync(cnt_src, 0, (size_t)N_NODES * 4, stream);
  hipMemsetAsync(cnt_dst, 0, (size_t)N_NODES * 4, stream);
  deg_src_kernel<<<2048, 256, 0, stream>>>(esrc, cnt_src);
  deg_dst_kernel<<<2048, 256, 0, stream>>>(edst, cnt_dst, rank);
  inv_kernel<<<(N_NODES + 255) / 256, 256, 0, stream>>>(cnt_src, cnt_dst, iso, isi);
  scan1_kernel<<<98, 256, 0, stream>>>(cnt_dst, csr_off, bsum);
  scan2_kernel<<<1, 1, 0, stream>>>(bsum, 98);
  scan3_kernel<<<98, 256, 0, stream>>>(csr_off, bsum);
  scatter_kernel<<<2048, 256, 0, stream>>>(esrc, edst, csr_off, rank, csr_src);

  // ---- weight + feature splits
  wsplit<<<64, 256, 0, stream>>>(W_emb, embt_h, embt_l, 128, 128);
  for (int l = 0; l < 3; ++l)
    wsplit<<<64, 256, 0, stream>>>(gcn_W + (size_t)l * 16384,
                                   gcnt_h + (size_t)l * 16384,
                                   gcnt_l + (size_t)l * 16384, 128, 128);
  wsplit<<<128, 256, 0, stream>>>(gW1, g1t_h, g1t_l, 256, 128);
  wsplit<<<32, 256, 0, stream>>>(gW2, g2t_h, g2t_l, 128, 64);
  wsplit<<<3, 256, 0, stream>>>(gW3, g3t_h, g3t_l, 64, 10);
  wsplit<<<288, 256, 0, stream>>>(nW1, n1t_h, n1t_l, 384, 192);
  wsplit<<<72, 256, 0, stream>>>(nW2, n2t_h, n2t_l, 192, 96);
  wsplit<<<4, 256, 0, stream>>>(nW3, n3t_h, n3t_l, 96, 10);
  split_pair<<<12512, 256, 0, stream>>>(feature, f_h, f_l, N_NODES * 32);

  // ---- embedding: x = feature @ W_emb + b_emb
  gemm_mfma<0,0><<<dim3(1564, 2), 256, 0, stream>>>(f_h, f_l, nullptr, nullptr,
                                                    embt_h, embt_l, b_emb,
                                                    x, nullptr, nullptr,
                                                    N_NODES, 128, 128, 0);

  // ---- GCN layers
  for (int l = 0; l < 3; ++l) {
    hipMemsetAsync(bnsum, 0, 1024, stream);
    agg_kernel<<<N_NODES / 4, 256, 0, stream>>>(x, csr_off, csr_src, iso, isi, agg_h, agg_l);
    gemm_mfma<0,0><<<dim3(1564, 2), 256, 0, stream>>>(agg_h, agg_l, nullptr, nullptr,
                                                      gcnt_h + (size_t)l * 16384,
                                                      gcnt_l + (size_t)l * 16384,
                                                      gcn_b + l * 128,
                                                      h, nullptr, nullptr,
                                                      N_NODES, 128, 128, 0);
    col_stats<<<512, 256, 0, stream>>>(h, bnsum);
    bn_finalize<<<1, 128, 0, stream>>>(bnsum, gcn_g + l * 128, gcn_be + l * 128, bnsc);
    bn_apply<<<2048, 256, 0, stream>>>(h, bnsc, x,
                                       (l == 2) ? x_h : nullptr,
                                       (l == 2) ? x_l : nullptr);
  }

  // ---- pooling (emits bf16 pair hg)
  pool_kernel<<<NGRAPH, 256, 0, stream>>>(x, hg_h, hg_l);

  // ---- graph head: 256 -> 128 -> 64 -> 10
  gemm_mfma<0,1><<<dim3(2, 2), 256, 0, stream>>>(hg_h, hg_l, nullptr, nullptr,
                                                 g1t_h, g1t_l, gb1,
                                                 nullptr, g1_h, g1_l, NGRAPH, 256, 128, 1);
  gemm_mfma<0,1><<<dim3(2, 1), 256, 0, stream>>>(g1_h, g1_l, nullptr, nullptr,
                                                 g2t_h, g2t_l, gb2,
                                                 nullptr, g2_h, g2_l, NGRAPH, 128, 64, 1);
  gemm_mfma<0,0><<<dim3(2, 1), 256, 0, stream>>>(g2_h, g2_l, nullptr, nullptr,
                                                 g3t_h, g3t_l, gb3,
                                                 outG, nullptr, nullptr, NGRAPH, 64, 10, 0);

  // ---- node head: concat(hg[seg], x) [N,384] -> 192 -> 96 -> 10
  gemm_mfma<1,1><<<dim3(1564, 3), 256, 0, stream>>>(hg_h, hg_l, x_h, x_l,
                                                    n1t_h, n1t_l, nb1,
                                                    nullptr, t1_h, t1_l, N_NODES, 384, 192, 1);
  gemm_mfma<0,1><<<dim3(1564, 2), 256, 0, stream>>>(t1_h, t1_l, nullptr, nullptr,
                                                    n2t_h, n2t_l, nb2,
                                                    nullptr, t2_h, t2_l, N_NODES, 192, 96, 1);
  gemm_mfma<0,0><<<dim3(1564, 1), 256, 0, stream>>>(t2_h, t2_l, nullptr, nullptr,
                                                    n3t_h, n3t_l, nb3,
                                                    outXG, nullptr, nullptr, N_NODES, 96, 10, 0);

  // ---- node labels
  label_kernel<<<(N_NODES + 255) / 256, 256, 0, stream>>>(labels, outLb);
}